// Round 1
// baseline (1107.797 us; speedup 1.0000x reference)
//
#include <hip/hip_runtime.h>
#include <math.h>

#define N_ENT 200000
#define N_USERS 100000
#define N_FACTORS 4
#define NREL1 25           // N_REL - 1
#define CH 64
#define N_EDGES 1000000
#define NNZ 1000000

// 1 / (2*sqrt(32))
#define SCORE_SCALE 0.08838834764831845f

// ---- monotonic float<->uint encoding for atomicMax on floats ----
__device__ __forceinline__ unsigned enc_f(float f) {
    unsigned u = __float_as_uint(f);
    return (u & 0x80000000u) ? ~u : (u | 0x80000000u);
}
__device__ __forceinline__ float dec_f(unsigned u) {
    return (u & 0x80000000u) ? __uint_as_float(u & 0x7FFFFFFFu)
                             : __uint_as_float(~u);
}

// ---- tiny precompute: Mvec[r] = (W W^T) weight[r]; wnorm[r]; disen[f][c] ----
__global__ void precompute_k(const float* __restrict__ W,       // [64,64]
                             const float* __restrict__ weight,  // [25,64]
                             const float* __restrict__ datt,    // [4,25]
                             float* __restrict__ Mvec,          // [25,64]
                             float* __restrict__ wnorm,         // [25]
                             float* __restrict__ disen) {       // [4,64]
    __shared__ float sW[64 * 64];
    __shared__ float sw[NREL1 * 64];
    __shared__ float sWWt[64 * 64];
    int tid = threadIdx.x;
    for (int i = tid; i < 64 * 64; i += 256) sW[i] = W[i];
    for (int i = tid; i < NREL1 * 64; i += 256) sw[i] = weight[i];
    __syncthreads();
    // WWt[i][j] = sum_k W[i][k]*W[j][k]
    for (int e = tid; e < 64 * 64; e += 256) {
        int i = e >> 6, j = e & 63;
        float s = 0.f;
        for (int k = 0; k < 64; ++k) s += sW[i * 64 + k] * sW[j * 64 + k];
        sWWt[e] = s;
    }
    __syncthreads();
    // Mvec[r][i] = sum_j WWt[i][j] * weight[r][j]
    for (int e = tid; e < NREL1 * 64; e += 256) {
        int r = e >> 6, i = e & 63;
        float s = 0.f;
        for (int j = 0; j < 64; ++j) s += sWWt[i * 64 + j] * sw[r * 64 + j];
        Mvec[e] = s;
    }
    for (int r = tid; r < NREL1; r += 256) {
        float s = 0.f;
        for (int j = 0; j < 64; ++j) { float v = sw[r * 64 + j]; s += v * v; }
        wnorm[r] = s;
    }
    // disen[f][c] = sum_r softmax(datt[f])[r] * weight[r][c]
    for (int e = tid; e < N_FACTORS * 64; e += 256) {
        int f = e >> 6, c = e & 63;
        float m = -1e30f;
        for (int r = 0; r < NREL1; ++r) m = fmaxf(m, datt[f * NREL1 + r]);
        float ssum = 0.f, acc = 0.f;
        for (int r = 0; r < NREL1; ++r) {
            float p = expf(datt[f * NREL1 + r] - m);
            ssum += p;
            acc += p * sw[r * 64 + c];
        }
        disen[e] = acc / ssum;
    }
}

// ---- P1: score_r[e] = dot(ent[head], Mvec[rel]) * scale; atomicMax per head ----
__global__ void p1_score_r(const float* __restrict__ ent,
                           const int* __restrict__ head,
                           const int* __restrict__ etype,
                           const float* __restrict__ Mvec,
                           float* __restrict__ edge_buf,
                           unsigned* __restrict__ max_r) {
    int gid = blockIdx.x * blockDim.x + threadIdx.x;
    int e = gid >> 6;
    int lane = threadIdx.x & 63;
    if (e >= N_EDGES) return;
    int h = head[e];
    int r = etype[e] - 1;
    float v = ent[h * 64 + lane] * Mvec[r * 64 + lane];
    for (int o = 32; o; o >>= 1) v += __shfl_xor(v, o);
    if (lane == 0) {
        float s = v * SCORE_SCALE;
        edge_buf[e] = s;
        atomicMax(&max_r[h], enc_f(s));
    }
}

// ---- P2: e = exp(score - max); denom += e; cnt += 1 ----
__global__ void p2_exp_r(const int* __restrict__ head,
                         float* __restrict__ edge_buf,
                         const unsigned* __restrict__ max_r,
                         float* __restrict__ denom_r,
                         unsigned* __restrict__ cnt) {
    int e = blockIdx.x * blockDim.x + threadIdx.x;
    if (e >= N_EDGES) return;
    int h = head[e];
    float ex = expf(edge_buf[e] - dec_f(max_r[h]));
    edge_buf[e] = ex;
    atomicAdd(&denom_r[h], ex);
    atomicAdd(&cnt[h], 1u);
}

// ---- P3: trip = dot(h_emb,t_emb) + rel_attn^2 * wnorm[r]; atomicMax ----
__global__ void p3_trip(const float* __restrict__ ent,
                        const int* __restrict__ head,
                        const int* __restrict__ tail,
                        const int* __restrict__ etype,
                        const float* __restrict__ denom_r,
                        const float* __restrict__ wnorm,
                        float* __restrict__ edge_buf,
                        unsigned* __restrict__ max_t) {
    int gid = blockIdx.x * blockDim.x + threadIdx.x;
    int e = gid >> 6;
    int lane = threadIdx.x & 63;
    if (e >= N_EDGES) return;
    int h = head[e];
    int t = tail[e];
    float v = ent[h * 64 + lane] * ent[t * 64 + lane];
    for (int o = 32; o; o >>= 1) v += __shfl_xor(v, o);
    if (lane == 0) {
        int r = etype[e] - 1;
        float ra = edge_buf[e] / denom_r[h];
        float trip = v + ra * ra * wnorm[r];
        edge_buf[e] = trip;
        atomicMax(&max_t[h], enc_f(trip));
    }
}

// ---- P4: e = exp(trip - max); denom_t += e ----
__global__ void p4_exp_t(const int* __restrict__ head,
                         float* __restrict__ edge_buf,
                         const unsigned* __restrict__ max_t,
                         float* __restrict__ denom_t) {
    int e = blockIdx.x * blockDim.x + threadIdx.x;
    if (e >= N_EDGES) return;
    int h = head[e];
    float ex = expf(edge_buf[e] - dec_f(max_t[h]));
    edge_buf[e] = ex;
    atomicAdd(&denom_t[h], ex);
}

// ---- P5: out[head] += t_emb * weight[r] * (e_t/denom_t) ----
__global__ void p5_agg(const float* __restrict__ ent,
                       const float* __restrict__ weight,
                       const int* __restrict__ head,
                       const int* __restrict__ tail,
                       const int* __restrict__ etype,
                       const float* __restrict__ denom_t,
                       const float* __restrict__ edge_buf,
                       float* __restrict__ out) {
    int gid = blockIdx.x * blockDim.x + threadIdx.x;
    int e = gid >> 6;
    int lane = threadIdx.x & 63;
    if (e >= N_EDGES) return;
    int h = head[e];
    int t = tail[e];
    int r = etype[e] - 1;
    float mask = edge_buf[e] / denom_t[h];
    float val = ent[t * 64 + lane] * weight[r * 64 + lane] * mask;
    atomicAdd(&out[h * 64 + lane], val);
}

// ---- P6: out[h][c] /= max(cnt[h],1) ----
__global__ void p6_fin(float* __restrict__ out, const unsigned* __restrict__ cnt) {
    int idx = blockIdx.x * blockDim.x + threadIdx.x;
    if (idx >= N_ENT * 64) return;
    out[idx] /= fmaxf((float)cnt[idx >> 6], 1.0f);
}

// ---- U1: user_agg[row] += ent[col] * val (accumulate into d_out user region) ----
__global__ void u1_agg(const float* __restrict__ ent,
                       const int* __restrict__ rows,
                       const int* __restrict__ cols,
                       const float* __restrict__ vals,
                       float* __restrict__ out_user) {
    int gid = blockIdx.x * blockDim.x + threadIdx.x;
    int i = gid >> 6;
    int lane = threadIdx.x & 63;
    if (i >= NNZ) return;
    int u = rows[i];
    int c = cols[i];
    float val = vals[i];
    atomicAdd(&out_user[u * 64 + lane], ent[c * 64 + lane] * val);
}

// ---- U2: out_user[u] *= (1 + softmax(user_emb[u]@latent^T) @ disen) ----
__global__ void u2_fin(const float* __restrict__ uemb,
                       const float* __restrict__ lat,     // [4,64]
                       const float* __restrict__ disen,   // [4,64]
                       float* __restrict__ out_user) {
    int gid = blockIdx.x * blockDim.x + threadIdx.x;
    int u = gid >> 6;
    int lane = threadIdx.x & 63;
    if (u >= N_USERS) return;
    float ue = uemb[u * 64 + lane];
    float d[N_FACTORS];
    for (int f = 0; f < N_FACTORS; ++f) {
        float v = ue * lat[f * 64 + lane];
        for (int o = 32; o; o >>= 1) v += __shfl_xor(v, o);
        d[f] = v;   // all lanes hold the dot
    }
    float m = fmaxf(fmaxf(d[0], d[1]), fmaxf(d[2], d[3]));
    float p[N_FACTORS];
    float s = 0.f;
    for (int f = 0; f < N_FACTORS; ++f) { p[f] = expf(d[f] - m); s += p[f]; }
    float inv = 1.0f / s;
    float g = 0.f;
    for (int f = 0; f < N_FACTORS; ++f) g += p[f] * inv * disen[f * 64 + lane];
    int o = u * 64 + lane;
    out_user[o] = out_user[o] * (1.0f + g);
}

extern "C" void kernel_launch(void* const* d_in, const int* in_sizes, int n_in,
                              void* d_out, int out_size, void* d_ws, size_t ws_size,
                              hipStream_t stream) {
    (void)in_sizes; (void)n_in; (void)out_size; (void)ws_size;
    const float* ent    = (const float*)d_in[0];
    const float* uemb   = (const float*)d_in[1];
    const float* lat    = (const float*)d_in[2];
    const int*   eidx   = (const int*)d_in[3];
    const int*   etype  = (const int*)d_in[4];
    const int*   urows  = (const int*)d_in[5];
    const int*   ucols  = (const int*)d_in[6];
    const float* uvals  = (const float*)d_in[7];
    const float* weight = (const float*)d_in[8];
    const float* datt   = (const float*)d_in[9];
    const float* W      = (const float*)d_in[10];

    const int* head = eidx;
    const int* tail = eidx + N_EDGES;
    float* out = (float*)d_out;
    float* out_user = out + (size_t)N_ENT * 64;

    // ws layout
    float*    denom_r = (float*)d_ws;
    float*    denom_t = denom_r + N_ENT;
    unsigned* cnt     = (unsigned*)(denom_t + N_ENT);
    unsigned* max_r   = cnt + N_ENT;
    unsigned* max_t   = max_r + N_ENT;
    float*    edge_buf = (float*)(max_t + N_ENT);
    float*    Mvec    = edge_buf + N_EDGES;
    float*    wnorm   = Mvec + NREL1 * 64;
    float*    disen   = wnorm + 32;

    // zero accumulators (max arrays: 0 encodes below all finite — valid -inf)
    hipMemsetAsync(d_out, 0, (size_t)(N_ENT + N_USERS) * 64 * sizeof(float), stream);
    hipMemsetAsync(d_ws, 0, (size_t)5 * N_ENT * sizeof(float), stream);

    precompute_k<<<1, 256, 0, stream>>>(W, weight, datt, Mvec, wnorm, disen);

    const int BLK = 256;
    const int WPB = BLK / 64;                       // 4 waves (edges) per block
    int gridE_w = (N_EDGES + WPB - 1) / WPB;        // wave-per-edge kernels
    int gridE_t = (N_EDGES + BLK - 1) / BLK;        // thread-per-edge kernels

    p1_score_r<<<gridE_w, BLK, 0, stream>>>(ent, head, etype, Mvec, edge_buf, max_r);
    p2_exp_r  <<<gridE_t, BLK, 0, stream>>>(head, edge_buf, max_r, denom_r, cnt);
    p3_trip   <<<gridE_w, BLK, 0, stream>>>(ent, head, tail, etype, denom_r, wnorm, edge_buf, max_t);
    p4_exp_t  <<<gridE_t, BLK, 0, stream>>>(head, edge_buf, max_t, denom_t);
    p5_agg    <<<gridE_w, BLK, 0, stream>>>(ent, weight, head, tail, etype, denom_t, edge_buf, out);
    p6_fin    <<<(N_ENT * 64 + BLK - 1) / BLK, BLK, 0, stream>>>(out, cnt);
    u1_agg    <<<(NNZ + WPB - 1) / WPB, BLK, 0, stream>>>(ent, urows, ucols, uvals, out_user);
    u2_fin    <<<(N_USERS + WPB - 1) / WPB, BLK, 0, stream>>>(uemb, lat, disen, out_user);
}